// Round 1
// baseline (136.457 us; speedup 1.0000x reference)
//
#include <hip/hip_runtime.h>
#include <stdint.h>
#include <stddef.h>

// Problem constants (from reference): V=50000, D=256, S=128, B=64
#define DD 256
#define SS 128
#define BB 64

typedef __bf16 bf16x8 __attribute__((ext_vector_type(8)));
typedef float  f32x4  __attribute__((ext_vector_type(4)));
typedef unsigned int u32x4 __attribute__((ext_vector_type(4)));
typedef unsigned int u32x2 __attribute__((ext_vector_type(2)));

// LDS tile layout: [col][s], row stride 136 bf16 (= 272 B, 16B aligned for ds_read_b128).
#define LSTRIDE 136
#define BUFSZ   (128 * LSTRIDE)   // ushort units per buffer

__device__ __forceinline__ unsigned short f2bf(float x) {
    union { float f; unsigned u; } v; v.f = x;
    unsigned r = v.u + 0x7FFFu + ((v.u >> 16) & 1u);   // RNE
    return (unsigned short)(r >> 16);
}

// One block = one (batch, 128x128 output tile). 4 blocks per batch, 256 blocks total.
// Buffers: 0 = w*R (d-slice), 1 = w*pos*C (d-slice), 2 = R (e-slice), 3 = pos*C (e-slice)
// real[d,e] = (wR)^T R + (wI)^T I ; imag[d,e] = (wI)^T R - (wR)^T I
__global__ __launch_bounds__(256, 1)
void cmp_density_kernel(const int*   __restrict__ questions,
                        const float* __restrict__ q_position,
                        const float* __restrict__ word_emb,
                        const float* __restrict__ cmp_emb,
                        const float* __restrict__ weighted_q,
                        float*       __restrict__ out)
{
    __shared__ unsigned short s16[4 * BUFSZ];   // 139,264 B
    __shared__ int   sQ[SS];
    __shared__ float sPos[SS];
    __shared__ float sW[SS];

    const int tid = threadIdx.x;
    const int bx  = blockIdx.x;
    const int b   = bx >> 2;
    const int td  = (bx >> 1) & 1;
    const int te  = bx & 1;

    if (tid < SS) {
        sQ[tid]   = questions[b * SS + tid];
        sPos[tid] = q_position[b * SS + tid];
        sW[tid]   = weighted_q[tid];
    }
    __syncthreads();

    // ---------------- staging: gather -> scale -> bf16 -> transposed LDS ----------------
    {
        const int sg = tid & 31;      // s-group of 4 rows
        const int cg = tid >> 5;      // 0..7
        const int s0 = sg * 4;
        int q[4]; float w_[4], p_[4];
        #pragma unroll
        for (int r = 0; r < 4; ++r) {
            q[r]  = sQ[s0 + r];
            w_[r] = sW[s0 + r];
            p_[r] = sPos[s0 + r];
        }
        #pragma unroll
        for (int pass = 0; pass < 4; ++pass) {
            const float* src = (pass == 0 || pass == 2) ? word_emb : cmp_emb;
            const int cb = (pass < 2) ? td * 128 : te * 128;
            unsigned short* dst = s16 + pass * BUFSZ;
            float scl[4];
            #pragma unroll
            for (int r = 0; r < 4; ++r)
                scl[r] = (pass == 0) ? w_[r]
                       : (pass == 1) ? w_[r] * p_[r]
                       : (pass == 2) ? 1.0f : p_[r];
            #pragma unroll
            for (int it = 0; it < 4; ++it) {
                const int c4 = cg + 8 * it;     // 0..31
                const int cl = 4 * c4;          // local col base
                f32x4 v[4];
                #pragma unroll
                for (int r = 0; r < 4; ++r)
                    v[r] = *(const f32x4*)(src + (size_t)q[r] * DD + cb + cl);
                #pragma unroll
                for (int r = 0; r < 4; ++r)
                    v[r] *= scl[r];
                #pragma unroll
                for (int j = 0; j < 4; ++j) {
                    unsigned lo = (unsigned)f2bf(v[0][j]) | ((unsigned)f2bf(v[1][j]) << 16);
                    unsigned hi = (unsigned)f2bf(v[2][j]) | ((unsigned)f2bf(v[3][j]) << 16);
                    u32x2 pk; pk.x = lo; pk.y = hi;
                    *(u32x2*)&dst[(cl + j) * LSTRIDE + s0] = pk;  // [col][s0..s0+3]
                }
            }
        }
    }
    __syncthreads();

    // ---------------- compute: 4 waves, each a 64x64 sub-tile ----------------
    const int lane = tid & 63;
    const int wv   = tid >> 6;
    const int wr   = wv >> 1;
    const int wc   = wv & 1;
    const int m    = lane & 15;     // A row / B col / C col
    const int kg   = lane >> 4;     // 0..3

    f32x4 accR[4][4] = {};
    f32x4 accI[4][4] = {};

    const unsigned short* pRw = s16;
    const unsigned short* pIw = s16 + BUFSZ;
    const unsigned short* pR  = s16 + 2 * BUFSZ;
    const unsigned short* pI  = s16 + 3 * BUFSZ;

    u32x4 sgnmask; sgnmask.x = sgnmask.y = sgnmask.z = sgnmask.w = 0x80008000u;

    #pragma unroll
    for (int ks = 0; ks < 4; ++ks) {
        const int k0 = ks * 32 + kg * 8;
        bf16x8 aR[4], aI[4], bR[4], bI[4], aRn[4];
        #pragma unroll
        for (int t = 0; t < 4; ++t) {
            const int ra = (wr * 64 + t * 16 + m) * LSTRIDE + k0;
            const int rb = (wc * 64 + t * 16 + m) * LSTRIDE + k0;
            aR[t] = *(const bf16x8*)(pRw + ra);
            aI[t] = *(const bf16x8*)(pIw + ra);
            bR[t] = *(const bf16x8*)(pR  + rb);
            bI[t] = *(const bf16x8*)(pI  + rb);
            u32x4 raw = __builtin_bit_cast(u32x4, aR[t]);
            raw ^= sgnmask;
            aRn[t] = __builtin_bit_cast(bf16x8, raw);
        }
        #pragma unroll
        for (int di = 0; di < 4; ++di) {
            #pragma unroll
            for (int ei = 0; ei < 4; ++ei) {
                accR[di][ei] = __builtin_amdgcn_mfma_f32_16x16x32_bf16(aR[di],  bR[ei], accR[di][ei], 0, 0, 0);
                accR[di][ei] = __builtin_amdgcn_mfma_f32_16x16x32_bf16(aI[di],  bI[ei], accR[di][ei], 0, 0, 0);
                accI[di][ei] = __builtin_amdgcn_mfma_f32_16x16x32_bf16(aI[di],  bR[ei], accI[di][ei], 0, 0, 0);
                accI[di][ei] = __builtin_amdgcn_mfma_f32_16x16x32_bf16(aRn[di], bI[ei], accI[di][ei], 0, 0, 0);
            }
        }
    }

    // ---------------- epilogue: C/D layout col=lane&15, row=(lane>>4)*4+reg ----------------
    float* outR = out + (size_t)b * DD * DD;
    float* outI = out + (size_t)BB * DD * DD + (size_t)b * DD * DD;
    const int d0 = td * 128 + wr * 64;
    const int e0 = te * 128 + wc * 64;
    #pragma unroll
    for (int di = 0; di < 4; ++di) {
        #pragma unroll
        for (int ei = 0; ei < 4; ++ei) {
            const int e = e0 + ei * 16 + m;
            #pragma unroll
            for (int r = 0; r < 4; ++r) {
                const int d = d0 + di * 16 + kg * 4 + r;
                outR[d * DD + e] = accR[di][ei][r];
                outI[d * DD + e] = accI[di][ei][r];
            }
        }
    }
}

extern "C" void kernel_launch(void* const* d_in, const int* in_sizes, int n_in,
                              void* d_out, int out_size, void* d_ws, size_t ws_size,
                              hipStream_t stream) {
    const int*   questions  = (const int*)d_in[0];
    const float* q_position = (const float*)d_in[1];
    const float* word_emb   = (const float*)d_in[2];
    const float* cmp_emb    = (const float*)d_in[3];
    const float* weighted_q = (const float*)d_in[4];
    float* out = (float*)d_out;
    (void)in_sizes; (void)n_in; (void)d_ws; (void)ws_size; (void)out_size;

    cmp_density_kernel<<<dim3(BB * 4), dim3(256), 0, stream>>>(
        questions, q_position, word_emb, cmp_emb, weighted_q, out);
}

// Round 3
// 135.486 us; speedup vs baseline: 1.0072x; 1.0072x over previous
//
#include <hip/hip_runtime.h>
#include <stdint.h>
#include <stddef.h>

// Problem constants: V=50000, D=256, S=128, B=64
#define DD 256
#define SS 128
#define BB 64

typedef __bf16 bf16x8 __attribute__((ext_vector_type(8)));
typedef float  f32x4  __attribute__((ext_vector_type(4)));
typedef unsigned int u32x4 __attribute__((ext_vector_type(4)));
typedef unsigned int u32x2 __attribute__((ext_vector_type(2)));

// LDS tile layout: [col][s], stride 136 bf16 (272 B, 16B-aligned rows).
#define LSTRIDE 136
#define BUFSZ   (128 * LSTRIDE)

__device__ __forceinline__ unsigned f2bf(float x) {
    union { float f; unsigned u; } v; v.f = x;
    unsigned r = v.u + 0x7FFFu + ((v.u >> 16) & 1u);   // RNE
    return r >> 16;
}

// Gather 64 global f32 per thread-chunk: rows q.{x,y,z,w}, 2 col-chunks of 16B.
// Wave-level: 16 rows x 64 B contiguous per instruction.
__device__ __forceinline__ void issue_loads(const float* __restrict__ src, const int4 q,
                                            int cb, int cg, f32x4 v[2][4]) {
    #pragma unroll
    for (int it = 0; it < 2; ++it) {
        const int cl = cb + 4 * (cg + 16 * it);
        v[it][0] = *(const f32x4*)(src + (size_t)q.x * DD + cl);
        v[it][1] = *(const f32x4*)(src + (size_t)q.y * DD + cl);
        v[it][2] = *(const f32x4*)(src + (size_t)q.z * DD + cl);
        v[it][3] = *(const f32x4*)(src + (size_t)q.w * DD + cl);
    }
}

// Scale rows, convert to bf16 (manual RNE), write transposed [col][s] as u32x2.
__device__ __forceinline__ void cvt_write(unsigned short* __restrict__ dst, const f32x4 scl,
                                          int s0, int cg, f32x4 v[2][4]) {
    #pragma unroll
    for (int it = 0; it < 2; ++it) {
        const int cll = 4 * (cg + 16 * it);
        f32x4 a = v[it][0] * scl[0];
        f32x4 b = v[it][1] * scl[1];
        f32x4 c = v[it][2] * scl[2];
        f32x4 d = v[it][3] * scl[3];
        #pragma unroll
        for (int j = 0; j < 4; ++j) {
            u32x2 pk;
            pk.x = f2bf(a[j]) | (f2bf(b[j]) << 16);
            pk.y = f2bf(c[j]) | (f2bf(d[j]) << 16);
            *(u32x2*)&dst[(cll + j) * LSTRIDE + s0] = pk;
        }
    }
}

// One K-step (32 wide) for 2 of the 4 di-tiles of a wave's 64x64 output pair.
// real += aR*bR + aI*bI ; imag += aI*bR - aR*bI (via sign-flipped aR).
template <int KS, int DI0>
__device__ __forceinline__ void mfma_part(const unsigned short* __restrict__ s,
                                          int wr, int wc, int m, int kg,
                                          f32x4 accR[4][4], f32x4 accI[4][4]) {
    const int k0 = KS * 32 + kg * 8;
    const unsigned short* pRw = s;
    const unsigned short* pIw = s + BUFSZ;
    const unsigned short* pR  = s + 2 * BUFSZ;
    const unsigned short* pI  = s + 3 * BUFSZ;
    bf16x8 bR[4], bI[4];
    #pragma unroll
    for (int t = 0; t < 4; ++t) {
        const int rb = (wc * 64 + t * 16 + m) * LSTRIDE + k0;
        bR[t] = *(const bf16x8*)(pR + rb);
        bI[t] = *(const bf16x8*)(pI + rb);
    }
    #pragma unroll
    for (int dd = 0; dd < 2; ++dd) {
        const int di = DI0 + dd;
        const int ra = (wr * 64 + di * 16 + m) * LSTRIDE + k0;
        bf16x8 aR = *(const bf16x8*)(pRw + ra);
        bf16x8 aI = *(const bf16x8*)(pIw + ra);
        u32x4 raw = __builtin_bit_cast(u32x4, aR) ^ 0x80008000u;
        bf16x8 aRn = __builtin_bit_cast(bf16x8, raw);
        #pragma unroll
        for (int ei = 0; ei < 4; ++ei) {
            accR[di][ei] = __builtin_amdgcn_mfma_f32_16x16x32_bf16(aR,  bR[ei], accR[di][ei], 0, 0, 0);
            accR[di][ei] = __builtin_amdgcn_mfma_f32_16x16x32_bf16(aI,  bI[ei], accR[di][ei], 0, 0, 0);
            accI[di][ei] = __builtin_amdgcn_mfma_f32_16x16x32_bf16(aI,  bR[ei], accI[di][ei], 0, 0, 0);
            accI[di][ei] = __builtin_amdgcn_mfma_f32_16x16x32_bf16(aRn, bI[ei], accI[di][ei], 0, 0, 0);
        }
    }
}

// Block = (batch, 128x128 quadrant). Buffers: 0=wR(d) 1=w*pos*C(d) 2=R(e) 3=pos*C(e).
// Pipelined: stage k-half0 -> barrier -> {gather k-half1 || MFMA ks=0,1} -> barrier -> ks=2,3.
__global__ __launch_bounds__(256, 1)
void cmp_density_kernel(const int*   __restrict__ questions,
                        const float* __restrict__ q_position,
                        const float* __restrict__ word_emb,
                        const float* __restrict__ cmp_emb,
                        const float* __restrict__ weighted_q,
                        float*       __restrict__ out)
{
    __shared__ __align__(16) unsigned short s16[4 * BUFSZ];   // 139,264 B

    const int tid = threadIdx.x;
    const int bx  = blockIdx.x;
    const int b   = bx >> 2;
    const int td  = (bx >> 1) & 1;
    const int te  = bx & 1;

    const int sg = tid & 15;        // s-group of 4 rows
    const int cg = tid >> 4;        // 0..15 col chunk
    const int lane = tid & 63;
    const int wv   = tid >> 6;
    const int wr   = wv >> 1;
    const int wc   = wv & 1;
    const int m    = lane & 15;
    const int kg   = lane >> 4;

    // Metadata, both k-halves, direct from global (16B vector loads).
    const int4  q0 = *(const int4*)(questions + b * SS + 4 * sg);
    const int4  q1 = *(const int4*)(questions + b * SS + 64 + 4 * sg);
    const f32x4 p0 = *(const f32x4*)(q_position + b * SS + 4 * sg);
    const f32x4 p1 = *(const f32x4*)(q_position + b * SS + 64 + 4 * sg);
    const f32x4 w0 = *(const f32x4*)(weighted_q + 4 * sg);
    const f32x4 w1 = *(const f32x4*)(weighted_q + 64 + 4 * sg);
    const f32x4 ones = {1.f, 1.f, 1.f, 1.f};

    f32x4 vA[2][4], vB[2][4];

    // ---- stage k-half 0 (s in [0,64)) ----
    issue_loads(word_emb, q0, td * 128, cg, vA);
    issue_loads(cmp_emb,  q0, td * 128, cg, vB);
    cvt_write(s16 + 0 * BUFSZ, w0,      4 * sg, cg, vA);
    cvt_write(s16 + 1 * BUFSZ, w0 * p0, 4 * sg, cg, vB);
    issue_loads(word_emb, q0, te * 128, cg, vA);
    issue_loads(cmp_emb,  q0, te * 128, cg, vB);
    cvt_write(s16 + 2 * BUFSZ, ones, 4 * sg, cg, vA);
    cvt_write(s16 + 3 * BUFSZ, p0,   4 * sg, cg, vB);
    __syncthreads();

    f32x4 accR[4][4] = {};
    f32x4 accI[4][4] = {};

    // ---- overlap: gather k-half 1 (s in [64,128)) while computing ks=0,1 ----
    issue_loads(word_emb, q1, td * 128, cg, vA);
    mfma_part<0, 0>(s16, wr, wc, m, kg, accR, accI);
    cvt_write(s16 + 0 * BUFSZ, w1, 64 + 4 * sg, cg, vA);
    issue_loads(cmp_emb, q1, td * 128, cg, vB);
    mfma_part<0, 2>(s16, wr, wc, m, kg, accR, accI);
    cvt_write(s16 + 1 * BUFSZ, w1 * p1, 64 + 4 * sg, cg, vB);
    issue_loads(word_emb, q1, te * 128, cg, vA);
    mfma_part<1, 0>(s16, wr, wc, m, kg, accR, accI);
    cvt_write(s16 + 2 * BUFSZ, ones, 64 + 4 * sg, cg, vA);
    issue_loads(cmp_emb, q1, te * 128, cg, vB);
    mfma_part<1, 2>(s16, wr, wc, m, kg, accR, accI);
    cvt_write(s16 + 3 * BUFSZ, p1, 64 + 4 * sg, cg, vB);
    __syncthreads();

    // ---- remaining K on half 1 ----
    mfma_part<2, 0>(s16, wr, wc, m, kg, accR, accI);
    mfma_part<2, 2>(s16, wr, wc, m, kg, accR, accI);
    mfma_part<3, 0>(s16, wr, wc, m, kg, accR, accI);
    mfma_part<3, 2>(s16, wr, wc, m, kg, accR, accI);

    // ---- epilogue: C/D layout col=lane&15, row=(lane>>4)*4+reg ----
    float* outR = out + (size_t)b * DD * DD;
    float* outI = out + (size_t)BB * DD * DD + (size_t)b * DD * DD;
    const int d0 = td * 128 + wr * 64;
    const int e0 = te * 128 + wc * 64;
    #pragma unroll
    for (int di = 0; di < 4; ++di) {
        #pragma unroll
        for (int ei = 0; ei < 4; ++ei) {
            const int e = e0 + ei * 16 + m;
            #pragma unroll
            for (int r = 0; r < 4; ++r) {
                const int d = d0 + di * 16 + kg * 4 + r;
                outR[d * DD + e] = accR[di][ei][r];
                outI[d * DD + e] = accI[di][ei][r];
            }
        }
    }
}

extern "C" void kernel_launch(void* const* d_in, const int* in_sizes, int n_in,
                              void* d_out, int out_size, void* d_ws, size_t ws_size,
                              hipStream_t stream) {
    const int*   questions  = (const int*)d_in[0];
    const float* q_position = (const float*)d_in[1];
    const float* word_emb   = (const float*)d_in[2];
    const float* cmp_emb    = (const float*)d_in[3];
    const float* weighted_q = (const float*)d_in[4];
    float* out = (float*)d_out;
    (void)in_sizes; (void)n_in; (void)d_ws; (void)ws_size; (void)out_size;

    cmp_density_kernel<<<dim3(BB * 4), dim3(256), 0, stream>>>(
        questions, q_position, word_emb, cmp_emb, weighted_q, out);
}